// Round 8
// baseline (205.473 us; speedup 1.0000x reference)
//
#include <hip/hip_runtime.h>
#include <hip/hip_bf16.h>
#include <math.h>

#define D_   64
#define HW_  4096
#define N_   16384
#define M_   4096

#define NSPLIT  16
#define NCHUNK  1024           // rows per block (n)
#define NTILES  8              // 8 tiles of 128 rows (4 waves x 32)
#define NBLOCKS 512

// ws float offsets
#define AZN_OFF 0                      // azn'[16384] (log2-domain, written phase A)
#define AEN_OFF 16384                  // aen'[4096]  (log2-domain, kernel 1)
#define SUM_OFF 20480                  // sums[4096]  (zeroed kernel 1)
#define CNT_OFF 24576                  // 2 uint counters + pad (kernel 1 zeroes)
#define ZTB_OFF 24592                  // zT bf16 [16384][64] = 524288 floats
#define EBF_OFF (24592 + 524288)       // e  bf16 [4096][64]

#define L2E 1.4426950408889634f
#define LN2 0.6931471805599453

typedef __attribute__((ext_vector_type(8))) short short8;
typedef __attribute__((ext_vector_type(16))) float floatx16;

#if __has_builtin(__builtin_amdgcn_exp2f)
#define EXP2F(x) __builtin_amdgcn_exp2f(x)
#else
#define EXP2F(x) exp2f(x)
#endif

__device__ __forceinline__ unsigned int bf16_rne(float x) {
    unsigned int u = __float_as_uint(x);
    u += 0x7fffu + ((u >> 16) & 1u);
    return u >> 16;
}

// kernel 1: 16 blocks — e->bf16 + aen' + zero sums + zero counters
__global__ void prep_e(const float* __restrict__ e,
                       const float* __restrict__ lsp,
                       float* __restrict__ ws) {
    const float ls = lsp[0];
    const float alpha = -0.5f * __expf(-2.f * ls);
    const float anl = alpha * L2E;
    unsigned short* ebf = (unsigned short*)(ws + EBF_OFF);
    int m = blockIdx.x * 256 + threadIdx.x;
    const float4* ep = (const float4*)(e + (size_t)m * D_);
    float s = 0.f;
    unsigned int pk[32];
#pragma unroll
    for (int k = 0; k < 16; ++k) {
        float4 v = ep[k];
        s += v.x * v.x + v.y * v.y + v.z * v.z + v.w * v.w;
        pk[2 * k]     = bf16_rne(v.x) | (bf16_rne(v.y) << 16);
        pk[2 * k + 1] = bf16_rne(v.z) | (bf16_rne(v.w) << 16);
    }
    uint4* op = (uint4*)(ebf + (size_t)m * 64);
#pragma unroll
    for (int k = 0; k < 8; ++k)
        op[k] = make_uint4(pk[4 * k], pk[4 * k + 1], pk[4 * k + 2], pk[4 * k + 3]);
    ws[AEN_OFF + m] = anl * s;
    ws[SUM_OFF + m] = 0.f;
    if (blockIdx.x == 0 && threadIdx.x < 2)
        ((unsigned*)(ws + CNT_OFF))[threadIdx.x] = 0u;
}

// kernel 2: 512 blocks — phase A z-transpose, grid barrier, main GEMM+exp, last block finalizes
__global__ __launch_bounds__(256, 3) void fused_kernel(
        const float* __restrict__ z, const float* __restrict__ lsp,
        float* __restrict__ ws, float* __restrict__ out) {
    __shared__ float shmem[2112];   // phase A: lt[64][33]; phase B: azn_l[1024]+red[128]; C: dred
    __shared__ int is_last;

    const int t = threadIdx.x;
    const int lane = t & 63;
    const int w = t >> 6;
    const int rlo = lane & 31;
    const int kh = lane >> 5;
    const int bx = (int)blockIdx.x;

    const float ls = lsp[0];
    const float alpha = -0.5f * __expf(-2.f * ls);
    const float anl = alpha * L2E;
    const float c2p = -2.f * alpha * L2E;

    unsigned short* zTb = (unsigned short*)(ws + ZTB_OFF);
    const unsigned short* ebf = (const unsigned short*)(ws + EBF_OFF);
    unsigned* cnt = (unsigned*)(ws + CNT_OFF);
    float* sums = ws + SUM_OFF;

    // B fragments loaded early (overlaps phase A latency); 128 e-rows resident
    const int mblk = bx & 31;
    const int ns = bx >> 5;
    const int m0 = mblk * 128;
    short8 bf[4][4];
#pragma unroll
    for (int mt = 0; mt < 4; ++mt) {
        int row = m0 + mt * 32 + rlo;
#pragma unroll
        for (int ks = 0; ks < 4; ++ks)
            bf[mt][ks] = *(const short8*)(ebf + (size_t)row * 64 + (ks * 2 + kh) * 8);
    }

    // ---- phase A: transpose one 64d x 32hw z-tile -> zTb + azn' ----
    {
        const int b = bx >> 7, hw0 = (bx & 127) * 32;
        const int n0 = b * HW_ + hw0;
        float* lt = shmem;   // [64][33]
#pragma unroll
        for (int i = 0; i < 2; ++i) {
            int idx = t + 256 * i;
            int d = idx >> 3, c = (idx & 7) * 4;
            float4 v = *(const float4*)(z + ((size_t)(b * D_ + d)) * HW_ + hw0 + c);
            float* p = &lt[d * 33 + c];
            p[0] = v.x; p[1] = v.y; p[2] = v.z; p[3] = v.w;
        }
        __syncthreads();
        const int nl = t >> 3, g = t & 7;
        float v[8]; float s = 0.f;
#pragma unroll
        for (int jj = 0; jj < 8; ++jj) {
            v[jj] = lt[(8 * g + jj) * 33 + nl];
            s = fmaf(v[jj], v[jj], s);
        }
        s += __shfl_xor(s, 1);
        s += __shfl_xor(s, 2);
        s += __shfl_xor(s, 4);
        uint4 pk;
        pk.x = bf16_rne(v[0] * c2p) | (bf16_rne(v[1] * c2p) << 16);
        pk.y = bf16_rne(v[2] * c2p) | (bf16_rne(v[3] * c2p) << 16);
        pk.z = bf16_rne(v[4] * c2p) | (bf16_rne(v[5] * c2p) << 16);
        pk.w = bf16_rne(v[6] * c2p) | (bf16_rne(v[7] * c2p) << 16);
        *(uint4*)(zTb + (size_t)(n0 + nl) * 64 + 8 * g) = pk;
        if (g == 0) ws[AZN_OFF + n0 + nl] = anl * s;
    }

    // ---- grid barrier (all 512 blocks co-resident: <=256 VGPR, 8.5 KB LDS) ----
    __threadfence();
    __syncthreads();
    if (t == 0) {
        __hip_atomic_fetch_add(&cnt[0], 1u, __ATOMIC_ACQ_REL, __HIP_MEMORY_SCOPE_AGENT);
        while (__hip_atomic_load(&cnt[0], __ATOMIC_ACQUIRE, __HIP_MEMORY_SCOPE_AGENT) < NBLOCKS)
            __builtin_amdgcn_s_sleep(1);
    }
    __syncthreads();
    __threadfence();

    // ---- phase B: load azn slice to LDS, then GEMM + exp2 ----
    float* azn_l = shmem;          // [1024]
    float* red = shmem + 1024;     // [128]
    {
        const float* azn_g = ws + AZN_OFF + ns * NCHUNK;
        float4 v = *(const float4*)(azn_g + 4 * t);
        *(float4*)&azn_l[4 * t] = v;
    }
    __syncthreads();

    float sum[4] = {0.f, 0.f, 0.f, 0.f};
    const size_t rowbase = (size_t)(ns * NCHUNK + w * 32 + rlo) * 64 + (size_t)kh * 8;

    short8 afc[4];
#pragma unroll
    for (int ks = 0; ks < 4; ++ks)
        afc[ks] = *(const short8*)(zTb + rowbase + ks * 16);

#pragma unroll
    for (int tile = 0; tile < NTILES; ++tile) {
        short8 afn[4];
        if (tile + 1 < NTILES) {
            const size_t rb = rowbase + (size_t)(tile + 1) * 128 * 64;
#pragma unroll
            for (int ks = 0; ks < 4; ++ks)
                afn[ks] = *(const short8*)(zTb + rb + ks * 16);
        }

        // azn for this wave's 16 C-rows (LDS broadcast reads)
        float azn_r[16];
        const int abase = w * 32 + tile * 128 + 4 * kh;
#pragma unroll
        for (int rg = 0; rg < 4; ++rg) {
            float4 vv = *(const float4*)&azn_l[abase + 8 * rg];
            azn_r[rg * 4 + 0] = vv.x; azn_r[rg * 4 + 1] = vv.y;
            azn_r[rg * 4 + 2] = vv.z; azn_r[rg * 4 + 3] = vv.w;
        }

        // two mt-pairs: acc[2] (32 VGPR) instead of acc[4]
#pragma unroll
        for (int p = 0; p < 2; ++p) {
            floatx16 acc[2];
#pragma unroll
            for (int m2 = 0; m2 < 2; ++m2)
#pragma unroll
                for (int r = 0; r < 16; ++r)
                    acc[m2][r] = azn_r[r];
#pragma unroll
            for (int ks = 0; ks < 4; ++ks)
#pragma unroll
                for (int m2 = 0; m2 < 2; ++m2)
                    acc[m2] = __builtin_amdgcn_mfma_f32_32x32x16_bf16(
                        afc[ks], bf[p * 2 + m2][ks], acc[m2], 0, 0, 0);
#pragma unroll
            for (int m2 = 0; m2 < 2; ++m2) {
                float s = 0.f;
#pragma unroll
                for (int r = 0; r < 16; ++r) s += EXP2F(acc[m2][r]);
                sum[p * 2 + m2] += s;
            }
        }

#pragma unroll
        for (int ks = 0; ks < 4; ++ks) afc[ks] = afn[ks];
    }

#pragma unroll
    for (int mt = 0; mt < 4; ++mt) sum[mt] += __shfl_down(sum[mt], 32);

    if (t < 128) red[t] = 0.f;
    __syncthreads();
    if (lane < 32) {
#pragma unroll
        for (int mt = 0; mt < 4; ++mt) atomicAdd(&red[mt * 32 + rlo], sum[mt]);
    }
    __syncthreads();
    if (t < 128) atomicAdd(&sums[m0 + t], red[t]);

    // ---- phase C: last-arriving block finalizes ----
    __threadfence();
    __syncthreads();
    if (t == 0) {
        unsigned old = __hip_atomic_fetch_add(&cnt[1], 1u, __ATOMIC_ACQ_REL,
                                              __HIP_MEMORY_SCOPE_AGENT);
        is_last = (old == NBLOCKS - 1);
    }
    __syncthreads();
    if (is_last) {
        __threadfence();
        const float* aen = ws + AEN_OFF;
        double local = 0.0;
#pragma unroll
        for (int j = 0; j < 16; ++j) {
            int m = t + 256 * j;
            float s = __hip_atomic_load(&sums[m], __ATOMIC_RELAXED,
                                        __HIP_MEMORY_SCOPE_AGENT);
            local += (double)(aen[m] + log2f(s));
        }
        double* dred = (double*)(shmem + 1280);
        dred[t] = local;
        __syncthreads();
        for (int off = 128; off > 0; off >>= 1) {
            if (t < off) dred[t] += dred[t + off];
            __syncthreads();
        }
        if (t == 0) {
            double lsd = (double)ls;
            double loss = -(LN2 * dred[0] / (double)M_)
                          + 0.5 * (double)D_ * (2.0 * lsd - 1.0)
                          + log((double)N_);
            out[0] = (float)loss;
        }
    }
}

extern "C" void kernel_launch(void* const* d_in, const int* in_sizes, int n_in,
                              void* d_out, int out_size, void* d_ws, size_t ws_size,
                              hipStream_t stream) {
    const float* z   = (const float*)d_in[0];
    const float* e   = (const float*)d_in[1];
    const float* lsp = (const float*)d_in[2];
    float* ws  = (float*)d_ws;
    float* out = (float*)d_out;

    hipLaunchKernelGGL(prep_e, dim3(16), dim3(256), 0, stream, e, lsp, ws);
    hipLaunchKernelGGL(fused_kernel, dim3(NBLOCKS), dim3(256), 0, stream,
                       z, lsp, ws, out);
}

// Round 9
// 95.322 us; speedup vs baseline: 2.1556x; 2.1556x over previous
//
#include <hip/hip_runtime.h>
#include <hip/hip_bf16.h>
#include <math.h>

#define D_   64
#define HW_  4096
#define N_   16384
#define M_   4096

// ---- geometry ----
#define BM 128                 // codes per block (e-rows register-resident)
#define NSPLIT 32              // n-splits across grid
#define NCHUNK (N_ / NSPLIT)   // 512 rows per block
#define NTILES (NCHUNK / 128)  // 4 tiles of 128 rows (4 waves x 32)

// ---- ws layout (floats) ----
#define AZN_OFF 0                      // azn'[16384]  (log2-domain row norms)
#define AEN_OFF 16384                  // aen'[4096]   (log2-domain col norms)
#define SUM_OFF 20480                  // sums[4096]
#define ZTB_OFF 24576                  // zT bf16 [16384][64] = 524288 floats
#define EBF_OFF (24576 + 524288)       // e  bf16 [4096][64]  = 131072 floats
#define WS_FLOATS (EBF_OFF + 131072)

#define L2E 1.4426950408889634f
#define LN2 0.6931471805599453

typedef __attribute__((ext_vector_type(8))) short short8;
typedef __attribute__((ext_vector_type(16))) float floatx16;

#if __has_builtin(__builtin_amdgcn_exp2f)
#define EXP2F(x) __builtin_amdgcn_exp2f(x)
#else
#define EXP2F(x) exp2f(x)
#endif

__device__ __forceinline__ unsigned int bf16_rne(float x) {
    unsigned int u = __float_as_uint(x);
    u += 0x7fffu + ((u >> 16) & 1u);
    return u >> 16;
}

// blocks 0..255: z transpose+scale+norm ; blocks 256..271: e convert+norm+zero sums
__global__ void prep_kernel(const float* __restrict__ z,
                            const float* __restrict__ e,
                            const float* __restrict__ lsp,
                            float* __restrict__ ws) {
    const float ls = lsp[0];
    const float alpha = -0.5f * __expf(-2.f * ls);   // -1/(2 e^{2ls})
    const float anl = alpha * L2E;                   // norm scale (log2 domain)
    const float c2p = -2.f * alpha * L2E;            // z pre-scale (log2 domain)
    unsigned short* zTb = (unsigned short*)(ws + ZTB_OFF);
    unsigned short* ebf = (unsigned short*)(ws + EBF_OFF);
    const int blk = blockIdx.x, t = threadIdx.x;

    if (blk < 256) {
        __shared__ float lt[64 * 65];
        const int b = blk >> 6, hw0 = (blk & 63) * 64;
        const int n0 = b * HW_ + hw0;
        const float* zb = z + ((size_t)b * D_) * HW_ + hw0;
#pragma unroll
        for (int i = 0; i < 4; ++i) {
            int idx = t + 256 * i;
            int d = idx >> 4, c = (idx & 15) * 4;
            float4 v = *(const float4*)(zb + (size_t)d * HW_ + c);
            float* p = &lt[d * 65 + c];
            p[0] = v.x; p[1] = v.y; p[2] = v.z; p[3] = v.w;
        }
        __syncthreads();
#pragma unroll
        for (int j = 0; j < 2; ++j) {
            int idx = t + 256 * j;
            int nl = idx >> 3, g = idx & 7;
            float v[8]; float s = 0.f;
#pragma unroll
            for (int jj = 0; jj < 8; ++jj) {
                v[jj] = lt[(8 * g + jj) * 65 + nl];
                s = fmaf(v[jj], v[jj], s);
            }
            s += __shfl_xor(s, 1);
            s += __shfl_xor(s, 2);
            s += __shfl_xor(s, 4);
            uint4 pk;
            pk.x = bf16_rne(v[0] * c2p) | (bf16_rne(v[1] * c2p) << 16);
            pk.y = bf16_rne(v[2] * c2p) | (bf16_rne(v[3] * c2p) << 16);
            pk.z = bf16_rne(v[4] * c2p) | (bf16_rne(v[5] * c2p) << 16);
            pk.w = bf16_rne(v[6] * c2p) | (bf16_rne(v[7] * c2p) << 16);
            *(uint4*)(zTb + (size_t)(n0 + nl) * 64 + 8 * g) = pk;
            if (g == 0) ws[AZN_OFF + n0 + nl] = anl * s;
        }
    } else {
        int m = (blk - 256) * 256 + t;
        const float4* ep = (const float4*)(e + (size_t)m * D_);
        float s = 0.f;
        unsigned int pk[32];
#pragma unroll
        for (int k = 0; k < 16; ++k) {
            float4 v = ep[k];
            s += v.x * v.x + v.y * v.y + v.z * v.z + v.w * v.w;
            pk[2 * k]     = bf16_rne(v.x) | (bf16_rne(v.y) << 16);
            pk[2 * k + 1] = bf16_rne(v.z) | (bf16_rne(v.w) << 16);
        }
        uint4* op = (uint4*)(ebf + (size_t)m * 64);
#pragma unroll
        for (int k = 0; k < 8; ++k)
            op[k] = make_uint4(pk[4 * k], pk[4 * k + 1], pk[4 * k + 2], pk[4 * k + 3]);
        ws[AEN_OFF + m] = anl * s;
        ws[SUM_OFF + m] = 0.f;
    }
}

// grid (32,32), 256 thr: B (e, 128 rows) register-resident; 4 A-tiles of 128 rows
// with register double-buffer prefetch; acc in mt-pairs (VGPR diet + MFMA/exp overlap);
// aen factored OUT (added in finalize).
__global__ __launch_bounds__(256, 3) void main_fast(float* __restrict__ ws) {
    __shared__ float lds_red[BM];
    const unsigned short* zTb = (const unsigned short*)(ws + ZTB_OFF);
    const unsigned short* ebf = (const unsigned short*)(ws + EBF_OFF);
    const float* azn = ws + AZN_OFF;
    float* sums = ws + SUM_OFF;

    const int m0 = blockIdx.x * BM;
    const int ns = blockIdx.y;
    const int t = threadIdx.x;
    const int lane = t & 63;
    const int w = t >> 6;
    const int rlo = lane & 31;
    const int kh = lane >> 5;

    // B fragments: 128 e-rows register-resident
    short8 bf[4][4];
#pragma unroll
    for (int mt = 0; mt < 4; ++mt) {
        int row = m0 + mt * 32 + rlo;
#pragma unroll
        for (int ks = 0; ks < 4; ++ks)
            bf[mt][ks] = *(const short8*)(ebf + (size_t)row * 64 + (ks * 2 + kh) * 8);
    }

    float sum[4] = {0.f, 0.f, 0.f, 0.f};
    const int nbase = ns * NCHUNK + w * 32;

    // prefetch tile 0
    short8 afc[4];
    float4 aznc[4];
    {
#pragma unroll
        for (int ks = 0; ks < 4; ++ks)
            afc[ks] = *(const short8*)(zTb + (size_t)(nbase + rlo) * 64 + (ks * 2 + kh) * 8);
        const int r0 = nbase + 4 * kh;
#pragma unroll
        for (int rg = 0; rg < 4; ++rg) aznc[rg] = *(const float4*)(azn + r0 + 8 * rg);
    }

#pragma unroll
    for (int tile = 0; tile < NTILES; ++tile) {
        short8 afn[4];
        float4 aznn[4];
        if (tile + 1 < NTILES) {
            const int nr = nbase + (tile + 1) * 128;
#pragma unroll
            for (int ks = 0; ks < 4; ++ks)
                afn[ks] = *(const short8*)(zTb + (size_t)(nr + rlo) * 64 + (ks * 2 + kh) * 8);
            const int r0 = nr + 4 * kh;
#pragma unroll
            for (int rg = 0; rg < 4; ++rg) aznn[rg] = *(const float4*)(azn + r0 + 8 * rg);
        }

        float azn_r[16];
#pragma unroll
        for (int rg = 0; rg < 4; ++rg) {
            azn_r[rg * 4 + 0] = aznc[rg].x; azn_r[rg * 4 + 1] = aznc[rg].y;
            azn_r[rg * 4 + 2] = aznc[rg].z; azn_r[rg * 4 + 3] = aznc[rg].w;
        }

        // two mt-pairs: acc[2] (32 VGPR) instead of acc[4]; pair p+1's MFMAs
        // overlap pair p's exp2 chain on the trans pipe
#pragma unroll
        for (int p = 0; p < 2; ++p) {
            floatx16 acc[2];
#pragma unroll
            for (int m2 = 0; m2 < 2; ++m2)
#pragma unroll
                for (int r = 0; r < 16; ++r)
                    acc[m2][r] = azn_r[r];          // aen factored out
#pragma unroll
            for (int ks = 0; ks < 4; ++ks)
#pragma unroll
                for (int m2 = 0; m2 < 2; ++m2)
                    acc[m2] = __builtin_amdgcn_mfma_f32_32x32x16_bf16(
                        afc[ks], bf[p * 2 + m2][ks], acc[m2], 0, 0, 0);
#pragma unroll
            for (int m2 = 0; m2 < 2; ++m2) {
                float s = 0.f;
#pragma unroll
                for (int r = 0; r < 16; ++r) s += EXP2F(acc[m2][r]);
                sum[p * 2 + m2] += s;
            }
        }

#pragma unroll
        for (int ks = 0; ks < 4; ++ks) afc[ks] = afn[ks];
#pragma unroll
        for (int rg = 0; rg < 4; ++rg) aznc[rg] = aznn[rg];
    }

#pragma unroll
    for (int mt = 0; mt < 4; ++mt) sum[mt] += __shfl_down(sum[mt], 32);

    if (t < BM) lds_red[t] = 0.f;
    __syncthreads();
    if (lane < 32) {
#pragma unroll
        for (int mt = 0; mt < 4; ++mt) atomicAdd(&lds_red[mt * 32 + rlo], sum[mt]);
    }
    __syncthreads();
    if (t < BM) atomicAdd(&sums[m0 + t], lds_red[t]);
}

__global__ void finalize_fast(const float* __restrict__ ws,
                              const float* __restrict__ lsp,
                              float* __restrict__ out) {
    __shared__ double red[256];
    const float* sums = ws + SUM_OFF;
    const float* aen = ws + AEN_OFF;
    int t = threadIdx.x;
    double local = 0.0;
#pragma unroll
    for (int j = 0; j < 16; ++j) {
        int m = t + 256 * j;
        // lse_m = ln2 * (aen'_m + log2(S_m))
        local += (double)(aen[m] + log2f(sums[m]));
    }
    red[t] = local;
    __syncthreads();
    for (int off = 128; off > 0; off >>= 1) {
        if (t < off) red[t] += red[t + off];
        __syncthreads();
    }
    if (t == 0) {
        double ls = (double)lsp[0];
        double loss = -(LN2 * red[0] / (double)M_)
                      + 0.5 * (double)D_ * (2.0 * ls - 1.0)
                      + log((double)N_);
        out[0] = (float)loss;
    }
}

extern "C" void kernel_launch(void* const* d_in, const int* in_sizes, int n_in,
                              void* d_out, int out_size, void* d_ws, size_t ws_size,
                              hipStream_t stream) {
    const float* z   = (const float*)d_in[0];
    const float* e   = (const float*)d_in[1];
    const float* lsp = (const float*)d_in[2];
    float* ws  = (float*)d_ws;
    float* out = (float*)d_out;

    hipLaunchKernelGGL(prep_kernel, dim3(272), dim3(256), 0, stream, z, e, lsp, ws);
    hipLaunchKernelGGL(main_fast, dim3(M_ / BM, NSPLIT), dim3(256), 0, stream, ws);
    hipLaunchKernelGGL(finalize_fast, dim3(1), dim3(256), 0, stream, ws, lsp, out);
}